// Round 18
// baseline (45.699 us; speedup 1.0000x reference)
//
#include <hip/hip_runtime.h>
#include <hip/hip_bf16.h>

typedef __attribute__((ext_vector_type(2)))  float f32x2;
typedef __attribute__((ext_vector_type(8)))  float f32x8;
typedef __attribute__((ext_vector_type(16))) float f32x16;
typedef __attribute__((ext_vector_type(2)))  __bf16 bf16x2;
typedef __attribute__((ext_vector_type(8)))  __bf16 bf16x8;
typedef __attribute__((ext_vector_type(4)))  unsigned int u32x4;

static __device__ __forceinline__ bf16x8 cvt8(f32x8 v) {
    return __builtin_convertvector(v, bf16x8);
}
static __device__ __forceinline__ unsigned int pkcvt(f32x2 v) {
    return __builtin_bit_cast(unsigned int, __builtin_convertvector(v, bf16x2));
}
static __device__ __forceinline__ f32x2 max2(f32x2 v) {
    const f32x2 z = {0.f, 0.f};
    return __builtin_elementwise_max(v, z);
}

#define MFMA32(A, B, C) __builtin_amdgcn_mfma_f32_32x32x16_bf16((A), (B), (C), 0, 0, 0)

// kperm(h,i) = (i&3) + 8*(i>>2) + 4h : 32x32 D-frag row held in reg i of
// lane-group h (bijection on [0,16)). A2/A3 K-orders kperm'd at init so D regs
// pack directly into the next B operand — zero cross-lane ops.
// R18: + s_setprio(1) around the compute block (T5 — applicable regime:
// independent waves, no barriers); b2 back to f32x2 (R16 form, -24 insts/iter).
__global__ __launch_bounds__(256, 4) void mlp3_mfma32(
    const float* __restrict__ x,
    const float* __restrict__ W1, const float* __restrict__ b1,
    const float* __restrict__ W2, const float* __restrict__ b2,
    const float* __restrict__ W3, const float* __restrict__ b3,
    float* __restrict__ out, int n)
{
    const int tid  = (int)threadIdx.x;
    const int lane = tid & 63;
    const int row  = lane & 31;   // A-frag row / B col (point)
    const int h    = lane >> 5;   // K-half selector
    const int wv   = tid >> 6;

    // ---- weight fragments / constants (resident) ----
    bf16x8 a1d, a1s;
    {
        f32x8 t = {0.f,0.f,0.f,0.f,0.f,0.f,0.f,0.f};
        if (h == 0) {                       // heads 0,1: row = hd*16 + j
            const int hd = row >> 4, j = row & 15;
            t[0] = W1[hd * 32 + j];
            t[1] = W1[hd * 32 + 16 + j];
            t[2] = b1[hd * 16 + j];         // k=2: b1 (x K-slot 2 = 1.0)
        }
        a1d = cvt8(t);
        f32x8 s = {0.f,0.f,0.f,0.f,0.f,0.f,0.f,0.f};
        if (h == 0 && row < 16) {           // head 2 in rows 0..15
            s[0] = W1[64 + row];
            s[1] = W1[80 + row];
            s[2] = b1[32 + row];
        }
        a1s = cvt8(s);
    }
    bf16x8 a2[3], a3[3];
    f32x2  b2p[3][4];
    #pragma unroll
    for (int e = 0; e < 3; ++e) {
        f32x8 t2v = {0.f,0.f,0.f,0.f,0.f,0.f,0.f,0.f};
        if (row < 16) {
            #pragma unroll
            for (int i = 0; i < 8; ++i) {
                const int k = (i & 3) + 8 * (i >> 2) + 4 * h;   // kperm(h,i)
                t2v[i] = W2[e * 256 + k * 16 + row];
            }
        }
        a2[e] = cvt8(t2v);
        f32x8 t3 = {0.f,0.f,0.f,0.f,0.f,0.f,0.f,0.f};
        if (row == e) {
            #pragma unroll
            for (int i = 0; i < 8; ++i) {
                const int k = (i & 3) + 8 * (i >> 2) + 4 * h;
                t3[i] = W3[e * 16 + k];
            }
        }
        a3[e] = cvt8(t3);
        #pragma unroll
        for (int j = 0; j < 4; ++j) {
            const int k0 = ((2*j) & 3) + 8 * ((2*j) >> 2) + 4 * h;
            const int k1 = ((2*j+1) & 3) + 8 * ((2*j+1) >> 2) + 4 * h;
            b2p[e][j] = (f32x2){ b2[e * 16 + k0], b2[e * 16 + k1] };
        }
    }
    const float b30 = b3[0], b31 = b3[1], b32 = b3[2];
    f32x16 zz;
    #pragma unroll
    for (int r = 0; r < 16; ++r) zz[r] = 0.f;

    const int xoff = (wv * 32 + row) * 8;    // bytes into 1024B x-chunk
    const int ooff = (wv * 32 + row) * 12;   // bytes into 1536B out-chunk (lane<32)

    const int nblk   = n >> 7;               // 128 points per block-iter
    const int stride = (int)gridDim.x;
    const size_t xstep = (size_t)stride * 1024;
    const size_t ostep = (size_t)stride * 1536;

    int cb = (int)blockIdx.x;
    const char* xp = (const char*)x + (size_t)cb * 1024 + xoff;
    char*       op = (char*)out + (size_t)cb * 1536 + ooff;

    float2 xv = *reinterpret_cast<const float2*>(xp);
    float3 pend;
    char*  paddr = nullptr;
    bool   pendv = false;

    while (true) {
        const bool more = (cb + stride) < nblk;
        float2 xn;
        if (more)                             // prefetch next iter's x
            xn = *reinterpret_cast<const float2*>(xp + xstep);

        // previous iteration's store issued here: drain deadline 8 MFMAs away
        if (pendv && lane < 32)
            *reinterpret_cast<float3*>(paddr) = pend;

        // B1 k-slots {x0, x1, 1.0, 0...}
        u32x4 bu = { pkcvt((f32x2){xv.x, xv.y}), 0x3F80u, 0u, 0u };
        const bf16x8 bx = __builtin_bit_cast(bf16x8, bu);

        // ---- compute block at raised priority (T5: independent-wave regime) ----
        __builtin_amdgcn_s_setprio(1);

        f32x16 t;
        u32x4 w0, w1, w2;
        t = MFMA32(a1d, bx, zz);              // heads 0,1
        #pragma unroll
        for (int j = 0; j < 4; ++j) {
            w0[j] = pkcvt(max2((f32x2){ t[2*j],     t[2*j + 1] }));
            w1[j] = pkcvt(max2((f32x2){ t[8 + 2*j], t[8 + 2*j + 1] }));
        }
        t = MFMA32(a1s, bx, zz);              // head 2 (reuses t's regs)
        #pragma unroll
        for (int j = 0; j < 4; ++j)
            w2[j] = pkcvt(max2((f32x2){ t[2*j], t[2*j + 1] }));
        const bf16x8 bh0 = __builtin_bit_cast(bf16x8, w0);
        const bf16x8 bh1 = __builtin_bit_cast(bf16x8, w1);
        const bf16x8 bh2 = __builtin_bit_cast(bf16x8, w2);

        f32x16 y;
        #pragma unroll
        for (int e = 0; e < 3; ++e) {
            const bf16x8 bh = (e == 0) ? bh0 : ((e == 1) ? bh1 : bh2);
            t = MFMA32(a2[e], bh, zz);
            u32x4 bw;
            #pragma unroll
            for (int j = 0; j < 4; ++j) {
                f32x2 q = max2((f32x2){ t[2*j], t[2*j + 1] } + b2p[e][j]);
                bw[j] = pkcvt(q);
            }
            const bf16x8 bt = __builtin_bit_cast(bf16x8, bw);
            y = MFMA32(a3[e], bt, (e == 0) ? zz : y);
        }

        __builtin_amdgcn_s_setprio(0);

        pend  = make_float3(y[0] + b30, y[1] + b31, y[2] + b32);
        paddr = op;
        pendv = true;

        if (!more) break;
        cb += stride;
        xp += xstep;
        op += ostep;
        xv = xn;
    }

    if (pendv && lane < 32)
        *reinterpret_cast<float3*>(paddr) = pend;
}

extern "C" void kernel_launch(void* const* d_in, const int* in_sizes, int n_in,
                              void* d_out, int out_size, void* d_ws, size_t ws_size,
                              hipStream_t stream) {
    const float* x  = (const float*)d_in[0];
    const float* W1 = (const float*)d_in[1];
    const float* b1 = (const float*)d_in[2];
    const float* W2 = (const float*)d_in[3];
    const float* b2 = (const float*)d_in[4];
    const float* W3 = (const float*)d_in[5];
    const float* b3 = (const float*)d_in[6];
    float* out = (float*)d_out;
    (void)d_ws; (void)ws_size; (void)n_in; (void)out_size;

    const int n = in_sizes[0] / 2;   // 4194304 points (32768 * 128)
    const int block = 256;
    const int grid = 2048;           // persistent: 16 chunk-iterations per block

    mlp3_mfma32<<<grid, block, 0, stream>>>(x, W1, b1, W2, b2, W3, b3, out, n);
}

// Round 19
// 45.581 us; speedup vs baseline: 1.0026x; 1.0026x over previous
//
#include <hip/hip_runtime.h>
#include <hip/hip_bf16.h>

typedef __attribute__((ext_vector_type(2)))  float f32x2;
typedef __attribute__((ext_vector_type(8)))  float f32x8;
typedef __attribute__((ext_vector_type(16))) float f32x16;
typedef __attribute__((ext_vector_type(2)))  __bf16 bf16x2;
typedef __attribute__((ext_vector_type(8)))  __bf16 bf16x8;
typedef __attribute__((ext_vector_type(4)))  unsigned int u32x4;

static __device__ __forceinline__ bf16x8 cvt8(f32x8 v) {
    return __builtin_convertvector(v, bf16x8);
}
static __device__ __forceinline__ unsigned int pkcvt(f32x2 v) {
    return __builtin_bit_cast(unsigned int, __builtin_convertvector(v, bf16x2));
}
static __device__ __forceinline__ f32x2 max2(f32x2 v) {
    const f32x2 z = {0.f, 0.f};
    return __builtin_elementwise_max(v, z);
}

#define MFMA32(A, B, C) __builtin_amdgcn_mfma_f32_32x32x16_bf16((A), (B), (C), 0, 0, 0)

// kperm(h,i) = (i&3) + 8*(i>>2) + 4h : 32x32 D-frag row held in reg i of
// lane-group h (bijection on [0,16)). A2/A3 K-orders kperm'd at init so D regs
// pack directly into the next B operand — zero cross-lane ops.
// R19: __launch_bounds__(256, 2) — 256-VGPR budget so the allocator keeps
// MFMA C/D in arch VGPRs instead of the AGPR half. Kills the ~150/iter
// v_accvgpr_read/write tax (the bloat every register-diet round failed to
// move). Occupancy was pinned at ~2.5 waves/SIMD regardless; nothing lost.
__global__ __launch_bounds__(256, 2) void mlp3_mfma32(
    const float* __restrict__ x,
    const float* __restrict__ W1, const float* __restrict__ b1,
    const float* __restrict__ W2, const float* __restrict__ b2,
    const float* __restrict__ W3, const float* __restrict__ b3,
    float* __restrict__ out, int n)
{
    const int tid  = (int)threadIdx.x;
    const int lane = tid & 63;
    const int row  = lane & 31;   // A-frag row / B col (point)
    const int h    = lane >> 5;   // K-half selector
    const int wv   = tid >> 6;

    // ---- weight fragments / constants (resident) ----
    bf16x8 a1d, a1s;
    {
        f32x8 t = {0.f,0.f,0.f,0.f,0.f,0.f,0.f,0.f};
        if (h == 0) {                       // heads 0,1: row = hd*16 + j
            const int hd = row >> 4, j = row & 15;
            t[0] = W1[hd * 32 + j];
            t[1] = W1[hd * 32 + 16 + j];
            t[2] = b1[hd * 16 + j];         // k=2: b1 (x K-slot 2 = 1.0)
        }
        a1d = cvt8(t);
        f32x8 s = {0.f,0.f,0.f,0.f,0.f,0.f,0.f,0.f};
        if (h == 0 && row < 16) {           // head 2 in rows 0..15
            s[0] = W1[64 + row];
            s[1] = W1[80 + row];
            s[2] = b1[32 + row];
        }
        a1s = cvt8(s);
    }
    bf16x8 a2[3], a3[3];
    f32x2  b2p[3][4];
    #pragma unroll
    for (int e = 0; e < 3; ++e) {
        f32x8 t2v = {0.f,0.f,0.f,0.f,0.f,0.f,0.f,0.f};
        if (row < 16) {
            #pragma unroll
            for (int i = 0; i < 8; ++i) {
                const int k = (i & 3) + 8 * (i >> 2) + 4 * h;   // kperm(h,i)
                t2v[i] = W2[e * 256 + k * 16 + row];
            }
        }
        a2[e] = cvt8(t2v);
        f32x8 t3 = {0.f,0.f,0.f,0.f,0.f,0.f,0.f,0.f};
        if (row == e) {
            #pragma unroll
            for (int i = 0; i < 8; ++i) {
                const int k = (i & 3) + 8 * (i >> 2) + 4 * h;
                t3[i] = W3[e * 16 + k];
            }
        }
        a3[e] = cvt8(t3);
        #pragma unroll
        for (int j = 0; j < 4; ++j) {
            const int k0 = ((2*j) & 3) + 8 * ((2*j) >> 2) + 4 * h;
            const int k1 = ((2*j+1) & 3) + 8 * ((2*j+1) >> 2) + 4 * h;
            b2p[e][j] = (f32x2){ b2[e * 16 + k0], b2[e * 16 + k1] };
        }
    }
    const float b30 = b3[0], b31 = b3[1], b32 = b3[2];
    f32x16 zz;
    #pragma unroll
    for (int r = 0; r < 16; ++r) zz[r] = 0.f;

    const int xoff = (wv * 32 + row) * 8;    // bytes into 1024B x-chunk
    const int ooff = (wv * 32 + row) * 12;   // bytes into 1536B out-chunk (lane<32)

    const int nblk   = n >> 7;               // 128 points per block-iter
    const int stride = (int)gridDim.x;
    const size_t xstep = (size_t)stride * 1024;
    const size_t ostep = (size_t)stride * 1536;

    int cb = (int)blockIdx.x;
    const char* xp = (const char*)x + (size_t)cb * 1024 + xoff;
    char*       op = (char*)out + (size_t)cb * 1536 + ooff;

    float2 xv = *reinterpret_cast<const float2*>(xp);
    float3 pend;
    char*  paddr = nullptr;
    bool   pendv = false;

    while (true) {
        const bool more = (cb + stride) < nblk;
        float2 xn;
        if (more)                             // prefetch next iter's x
            xn = *reinterpret_cast<const float2*>(xp + xstep);

        // previous iteration's store issued here: drain deadline 8 MFMAs away
        if (pendv && lane < 32)
            *reinterpret_cast<float3*>(paddr) = pend;

        // B1 k-slots {x0, x1, 1.0, 0...}
        u32x4 bu = { pkcvt((f32x2){xv.x, xv.y}), 0x3F80u, 0u, 0u };
        const bf16x8 bx = __builtin_bit_cast(bf16x8, bu);

        // ---- Layer 1, serialized through ONE temp t ----
        f32x16 t;
        u32x4 w0, w1, w2;
        t = MFMA32(a1d, bx, zz);              // heads 0,1
        #pragma unroll
        for (int j = 0; j < 4; ++j) {
            w0[j] = pkcvt(max2((f32x2){ t[2*j],     t[2*j + 1] }));
            w1[j] = pkcvt(max2((f32x2){ t[8 + 2*j], t[8 + 2*j + 1] }));
        }
        t = MFMA32(a1s, bx, zz);              // head 2 (reuses t's regs)
        #pragma unroll
        for (int j = 0; j < 4; ++j)
            w2[j] = pkcvt(max2((f32x2){ t[2*j], t[2*j + 1] }));
        const bf16x8 bh0 = __builtin_bit_cast(bf16x8, w0);
        const bf16x8 bh1 = __builtin_bit_cast(bf16x8, w1);
        const bf16x8 bh2 = __builtin_bit_cast(bf16x8, w2);

        // ---- Layers 2+3 per head; y chained in place through MFMA3's C ----
        f32x16 y;
        #pragma unroll
        for (int e = 0; e < 3; ++e) {
            const bf16x8 bh = (e == 0) ? bh0 : ((e == 1) ? bh1 : bh2);
            t = MFMA32(a2[e], bh, zz);
            u32x4 bw;
            #pragma unroll
            for (int j = 0; j < 4; ++j) {
                f32x2 q = max2((f32x2){ t[2*j], t[2*j + 1] } + b2p[e][j]);
                bw[j] = pkcvt(q);
            }
            const bf16x8 bt = __builtin_bit_cast(bf16x8, bw);
            y = MFMA32(a3[e], bt, (e == 0) ? zz : y);
        }

        pend  = make_float3(y[0] + b30, y[1] + b31, y[2] + b32);
        paddr = op;
        pendv = true;

        if (!more) break;
        cb += stride;
        xp += xstep;
        op += ostep;
        xv = xn;
    }

    if (pendv && lane < 32)
        *reinterpret_cast<float3*>(paddr) = pend;
}

extern "C" void kernel_launch(void* const* d_in, const int* in_sizes, int n_in,
                              void* d_out, int out_size, void* d_ws, size_t ws_size,
                              hipStream_t stream) {
    const float* x  = (const float*)d_in[0];
    const float* W1 = (const float*)d_in[1];
    const float* b1 = (const float*)d_in[2];
    const float* W2 = (const float*)d_in[3];
    const float* b2 = (const float*)d_in[4];
    const float* W3 = (const float*)d_in[5];
    const float* b3 = (const float*)d_in[6];
    float* out = (float*)d_out;
    (void)d_ws; (void)ws_size; (void)n_in; (void)out_size;

    const int n = in_sizes[0] / 2;   // 4194304 points (32768 * 128)
    const int block = 256;
    const int grid = 2048;           // persistent: 16 chunk-iterations per block

    mlp3_mfma32<<<grid, block, 0, stream>>>(x, W1, b1, W2, b2, W3, b3, out, n);
}